// Round 4
// baseline (151.691 us; speedup 1.0000x reference)
//
#include <hip/hip_runtime.h>
#include <hip/hip_bf16.h>
#include <stdint.h>

typedef __attribute__((ext_vector_type(4))) float f32x4;
typedef __attribute__((ext_vector_type(8))) __bf16 bf16x8;

#define AS1 __attribute__((address_space(1)))
#define AS3 __attribute__((address_space(3)))

#if __has_builtin(__builtin_amdgcn_exp2f)
#define EXP2(x) __builtin_amdgcn_exp2f(x)
#else
#define EXP2(x) exp2f(x)
#endif

__device__ __forceinline__ ushort f2bf(float f) {
  uint32_t u = __builtin_bit_cast(uint32_t, f);
  u += 0x7fffu + ((u >> 16) & 1u);
  return (ushort)(u >> 16);
}
__device__ __forceinline__ float bf2f(ushort h) {
  uint32_t u = ((uint32_t)h) << 16;
  return __builtin_bit_cast(float, u);
}

#define SCK 0.18033688011112042f

#define GLD(src, dst) \
  __builtin_amdgcn_global_load_lds((const AS1 uint32_t*)(src), (AS3 uint32_t*)(dst), 16, 0, 0)

#define BARRIER()                          \
  do {                                     \
    __builtin_amdgcn_sched_barrier(0);     \
    __builtin_amdgcn_s_barrier();          \
    __builtin_amdgcn_sched_barrier(0);     \
  } while (0)

// ---------------- elementwise converts ----------------

__global__ void k_cvt_x(const float* __restrict__ x, ushort* __restrict__ xb, int n4) {
  int i = blockIdx.x * blockDim.x + threadIdx.x;
  if (i >= n4) return;
  float4 v = ((const float4*)x)[i];
  ushort4 o;
  o.x = f2bf(v.x); o.y = f2bf(v.y); o.z = f2bf(v.z); o.w = f2bf(v.w);
  ((ushort4*)xb)[i] = o;
}

__global__ void k_prep_w(const float* __restrict__ Wq, const float* __restrict__ Wk,
                         const float* __restrict__ Wv, const float* __restrict__ Wo,
                         ushort* __restrict__ Wt, ushort* __restrict__ Wot) {
  __shared__ float tile[32][33];
  int z = blockIdx.z;
  const float* src = (z == 0) ? Wq : (z == 1) ? Wk : (z == 2) ? Wv : Wo;
  ushort* dst = (z < 3) ? (Wt + (size_t)z * 1048576) : Wot;
  float scale = (z == 1) ? SCK : 1.0f;
  int k0 = blockIdx.y * 32, n0 = blockIdx.x * 32;
  int tx = threadIdx.x, ty = threadIdx.y;
#pragma unroll
  for (int i = 0; i < 4; i++)
    tile[ty + i * 8][tx] = src[(size_t)(k0 + ty + i * 8) * 1024 + n0 + tx];
  __syncthreads();
#pragma unroll
  for (int i = 0; i < 4; i++)
    dst[(size_t)(n0 + ty + i * 8) * 1024 + k0 + tx] = f2bf(tile[tx][ty + i * 8] * scale);
}

// ---------------- 256x256 pipelined GEMM, 2 sub-phases per K-tile ----------------
template <int MODE>
__global__ __launch_bounds__(512, 2) void k_gemm8(const ushort* __restrict__ A,
                                                  const ushort* __restrict__ Bt,
                                                  void* __restrict__ Cv,
                                                  const float* __restrict__ b0,
                                                  const float* __restrict__ b1,
                                                  const float* __restrict__ b2,
                                                  int K, int ldc) {
  __shared__ char ldsb[131072];
  const int tid = threadIdx.x;
  const int lane = tid & 63;
  const int wid = tid >> 6;
  const int wr = wid >> 2, wc = wid & 3;
  const int l15 = lane & 15, l4 = lane >> 4;
  const int row0 = blockIdx.y * 256;
  const int col0 = blockIdx.x * 256;
  const int T = K >> 5;

  const int swz = ((tid & 3) ^ ((tid >> 3) & 3)) << 3;
  const ushort* Ap = A + (size_t)(row0 + (tid >> 2)) * K + swz;
  const ushort* Bp = Bt + (size_t)(col0 + (tid >> 2)) * K + swz;

#define STAGE_H1(t)                              \
  do {                                           \
    char* bufs = ldsb + (((t) & 3) << 15);       \
    const ushort* pa = Ap + (size_t)(t) * 32;    \
    GLD(pa, bufs + tid * 16);                    \
    GLD(pa + 128 * K, bufs + 8192 + tid * 16);   \
  } while (0)
#define STAGE_H2(t)                              \
  do {                                           \
    char* bufs = ldsb + (((t) & 3) << 15);       \
    const ushort* pb = Bp + (size_t)(t) * 32;    \
    GLD(pb, bufs + 16384 + tid * 16);            \
    GLD(pb + 24576 - 16384 + 16384 + 8192 - 8192 + 8192 * 0 + 128 * K * 2 / 2, 0); \
  } while (0)
#undef STAGE_H2
#define STAGE_H2(t)                              \
  do {                                           \
    char* bufs = ldsb + (((t) & 3) << 15);       \
    const ushort* pb = Bp + (size_t)(t) * 32;    \
    GLD(pb, bufs + 16384 + tid * 16);            \
    GLD(pb + 128 * K, bufs + 24576 + tid * 16);  \
  } while (0)

  int aoffL[8], boffL[4];
#pragma unroll
  for (int m = 0; m < 8; m++) {
    int r = wr * 128 + m * 16 + l15;
    aoffL[m] = r * 64 + ((l4 ^ ((r >> 1) & 3)) << 4);
  }
#pragma unroll
  for (int n = 0; n < 4; n++) {
    int r = wc * 64 + n * 16 + l15;
    boffL[n] = 16384 + r * 64 + ((l4 ^ ((r >> 1) & 3)) << 4);
  }

  f32x4 acc[8][4] = {};

  STAGE_H1(0); STAGE_H2(0);
  STAGE_H1(1); STAGE_H2(1);
  STAGE_H1(2); STAGE_H2(2);
  asm volatile("s_waitcnt vmcnt(8)" ::: "memory");
  BARRIER();

#define PHASE(t, DO_STAGE, VMSTR)                                                     \
  do {                                                                                \
    char* buf = ldsb + (((t) & 3) << 15);                                             \
    /* sub-phase A: B frags + A lower half */                                         \
    {                                                                                 \
      bf16x8 af[4], bfr[4];                                                           \
      _Pragma("unroll") for (int m = 0; m < 4; m++)                                   \
          af[m] = *(const bf16x8*)(buf + aoffL[m]);                                   \
      _Pragma("unroll") for (int n = 0; n < 4; n++)                                   \
          bfr[n] = *(const bf16x8*)(buf + boffL[n]);                                  \
      if (DO_STAGE) STAGE_H1((t) + 3);                                                \
      BARRIER();                                                                      \
      __builtin_amdgcn_s_setprio(1);                                                  \
      _Pragma("unroll") for (int m = 0; m < 4; m++)                                   \
          _Pragma("unroll") for (int n = 0; n < 4; n++)                               \
              acc[m][n] = __builtin_amdgcn_mfma_f32_16x16x32_bf16(af[m], bfr[n],      \
                                                                  acc[m][n], 0, 0, 0);\
      __builtin_amdgcn_s_setprio(0);                                                  \
      /* keep bfr live into sub-phase B via recompute-free reuse */                   \
      BARRIER();                                                                      \
      /* sub-phase B: A upper half, reuse B frags */                                  \
      bf16x8 af2[4];                                                                  \
      _Pragma("unroll") for (int m = 0; m < 4; m++)                                   \
          af2[m] = *(const bf16x8*)(buf + aoffL[m + 4]);                              \
      if (DO_STAGE) STAGE_H2((t) + 3);                                                \
      BARRIER();                                                                      \
      __builtin_amdgcn_s_setprio(1);                                                  \
      _Pragma("unroll") for (int m = 0; m < 4; m++)                                   \
          _Pragma("unroll") for (int n = 0; n < 4; n++)                               \
              acc[m + 4][n] = __builtin_amdgcn_mfma_f32_16x16x32_bf16(                \
                  af2[m], bfr[n], acc[m + 4][n], 0, 0, 0);                            \
      __builtin_amdgcn_s_setprio(0);                                                  \
      asm volatile(VMSTR ::: "memory");                                               \
      BARRIER();                                                                      \
    }                                                                                 \
  } while (0)

  for (int t = 0; t < T - 3; ++t) PHASE(t, true, "s_waitcnt vmcnt(8)");
  PHASE(T - 3, false, "s_waitcnt vmcnt(4)");
  PHASE(T - 2, false, "s_waitcnt vmcnt(0)");
  PHASE(T - 1, false, "s_nop 0");

#undef PHASE
#undef STAGE_H1
#undef STAGE_H2

#pragma unroll
  for (int m = 0; m < 8; m++)
#pragma unroll
    for (int n = 0; n < 4; n++) {
      int colg = col0 + wc * 64 + n * 16 + l15;
      float bias;
      if (MODE == 0) {
        bias = (colg < 1024) ? b0[colg]
                             : ((colg < 2048) ? b1[colg - 1024] * SCK : b2[colg - 2048]);
      } else {
        bias = b0[colg];
      }
#pragma unroll
      for (int j = 0; j < 4; j++) {
        int rowg = row0 + wr * 128 + m * 16 + l4 * 4 + j;
        float v = acc[m][n][j] + bias;
        if (MODE == 0)
          ((ushort*)Cv)[(size_t)rowg * ldc + colg] = f2bf(v);
        else
          ((float*)Cv)[(size_t)rowg * ldc + colg] = v;
      }
    }
}

// ---------------- 128x128 2-phase GEMM for the output projection ----------------
template <int MODE>
__global__ __launch_bounds__(256) void k_gemm(const ushort* __restrict__ A,
                                              const ushort* __restrict__ Bt,
                                              void* __restrict__ Cv,
                                              const float* __restrict__ b0,
                                              int M, int N, int K, int ldc) {
  __shared__ ushort As[128 * 32];
  __shared__ ushort Bs[128 * 32];
  const int tid = threadIdx.x;
  const int lane = tid & 63;
  const int wid = tid >> 6;
  const int wr = wid >> 1, wc = wid & 1;
  const int row0 = blockIdx.y * 128;
  const int col0 = blockIdx.x * 128;
  const int l15 = lane & 15, l4 = lane >> 4;

  f32x4 acc[4][4] = {};

  for (int k0 = 0; k0 < K; k0 += 32) {
    __syncthreads();
#pragma unroll
    for (int i = 0; i < 2; i++) {
      int c = i * 256 + tid;
      int r = c >> 2, cb = c & 3;
      GLD(A + (size_t)(row0 + r) * K + k0 + cb * 8, (char*)As + c * 16);
      GLD(Bt + (size_t)(col0 + r) * K + k0 + cb * 8, (char*)Bs + c * 16);
    }
    __syncthreads();
    bf16x8 av[4], bv[4];
#pragma unroll
    for (int m = 0; m < 4; m++)
      av[m] = *(const bf16x8*)(As + (wr * 64 + m * 16 + l15) * 32 + l4 * 8);
#pragma unroll
    for (int n = 0; n < 4; n++)
      bv[n] = *(const bf16x8*)(Bs + (wc * 64 + n * 16 + l15) * 32 + l4 * 8);
#pragma unroll
    for (int m = 0; m < 4; m++)
#pragma unroll
      for (int n = 0; n < 4; n++)
        acc[m][n] = __builtin_amdgcn_mfma_f32_16x16x32_bf16(av[m], bv[n], acc[m][n], 0, 0, 0);
  }

#pragma unroll
  for (int m = 0; m < 4; m++)
#pragma unroll
    for (int n = 0; n < 4; n++) {
      int colg = col0 + wc * 64 + n * 16 + l15;
      float bias = b0[colg];
#pragma unroll
      for (int j = 0; j < 4; j++) {
        int rowg = row0 + wr * 64 + m * 16 + l4 * 4 + j;
        float v = acc[m][n][j] + bias;
        if (MODE == 0)
          ((ushort*)Cv)[(size_t)rowg * ldc + colg] = f2bf(v);
        else
          ((float*)Cv)[(size_t)rowg * ldc + colg] = v;
      }
    }
}

// ---------------- attention pass 1: Z[tk] = sum_tq exp2(S) ----------------
// grid (tkb=8, bh=32, s=2); 256 thr = 4 waves; wave w owns tk rows w*64..+64.
// K tile 256x64 static; Q tiles 128x64, 3-buffer ring, counted vmcnt.
__global__ __launch_bounds__(256, 2) void k_attn_z(const ushort* __restrict__ QKV,
                                                   float* __restrict__ Zpart) {
  const int tkb = blockIdx.x, bh = blockIdx.y, s = blockIdx.z;
  const int b = bh >> 4, h = bh & 15;
  const int tid = threadIdx.x, lane = tid & 63, w = tid >> 6;
  const int l15 = lane & 15, l4 = lane >> 4;
  const size_t rs = 3072;

  __shared__ ushort Ks[256 * 64];          // 32 KB
  __shared__ ushort Qs[3][128 * 64];       // 48 KB

  const ushort* Kbase = QKV + (size_t)(b * 2048 + tkb * 256) * rs + 1024 + h * 64;
  const ushort* Qbase = QKV + (size_t)(b * 2048 + s * 1024) * rs + h * 64;

  const int csl = ((tid & 7) ^ ((tid >> 3) & 7)) * 8;  // pre-swizzled src ushort offset

  // stage K (8 chunks/thread) + Q0 + Q1
#pragma unroll
  for (int i = 0; i < 8; i++) {
    int c = i * 256 + tid;
    GLD(Kbase + (size_t)(c >> 3) * rs + csl, (char*)Ks + c * 16);
  }
  const ushort* gq[4];
#pragma unroll
  for (int i = 0; i < 4; i++) {
    int c = i * 256 + tid;
    gq[i] = Qbase + (size_t)(c >> 3) * rs + csl;
    GLD(gq[i], (char*)Qs[0] + c * 16);
    GLD(gq[i] + 128 * rs, (char*)Qs[1] + c * 16);
  }
  asm volatile("s_waitcnt vmcnt(8)" ::: "memory");
  BARRIER();

  bf16x8 kf[4][2];
#pragma unroll
  for (int m = 0; m < 4; m++)
#pragma unroll
    for (int d = 0; d < 2; d++) {
      int r = w * 64 + m * 16 + l15;
      kf[m][d] = *(const bf16x8*)((const char*)Ks + r * 128 + (((d * 4 + l4) ^ (r & 7)) << 4));
    }

  float z[4][4] = {};
  const f32x4 zero4 = {0.f, 0.f, 0.f, 0.f};

  for (int t = 0; t < 8; ++t) {
    if (t < 7)
      asm volatile("s_waitcnt vmcnt(4)" ::: "memory");
    else
      asm volatile("s_waitcnt vmcnt(0)" ::: "memory");
    BARRIER();
    if (t < 6) {
      char* qd = (char*)Qs[(t + 2) % 3];
#pragma unroll
      for (int i = 0; i < 4; i++) {
        int c = i * 256 + tid;
        GLD(gq[i] + (size_t)(t + 2) * 128 * rs, qd + c * 16);
      }
    }
    const char* qb = (const char*)Qs[t % 3];
    f32x4 acc[4][8];
#pragma unroll
    for (int d = 0; d < 2; d++)
#pragma unroll
      for (int n = 0; n < 8; n++) {
        int r = n * 16 + l15;
        bf16x8 qf = *(const bf16x8*)(qb + r * 128 + (((d * 4 + l4) ^ (r & 7)) << 4));
#pragma unroll
        for (int m = 0; m < 4; m++)
          acc[m][n] = __builtin_amdgcn_mfma_f32_16x16x32_bf16(
              kf[m][d], qf, d == 0 ? zero4 : acc[m][n], 0, 0, 0);
      }
#pragma unroll
    for (int m = 0; m < 4; m++)
#pragma unroll
      for (int n = 0; n < 8; n++)
#pragma unroll
        for (int j = 0; j < 4; j++) z[m][j] += EXP2(acc[m][n][j]);
  }

#pragma unroll
  for (int m = 0; m < 4; m++)
#pragma unroll
    for (int j = 0; j < 4; j++) {
      float v = z[m][j];
      v += __shfl_xor(v, 1, 64);
      v += __shfl_xor(v, 2, 64);
      v += __shfl_xor(v, 4, 64);
      v += __shfl_xor(v, 8, 64);
      if (l15 == 0)
        Zpart[(size_t)s * 65536 + bh * 2048 + tkb * 256 + w * 64 + m * 16 + l4 * 4 + j] = v;
    }
}

__global__ void k_rz(const float* __restrict__ Zpart, float* __restrict__ rrz) {
  int g = blockIdx.x * 256 + threadIdx.x;
  rrz[g] = 1.0f / (Zpart[g] + Zpart[65536 + g]);
}

// ---------------- attention pass 2: colsum[tq] = sum_tk exp2(S)*rrz[tk] ----
__global__ __launch_bounds__(256, 2) void k_attn_cs(const ushort* __restrict__ QKV,
                                                    const float* __restrict__ rrz,
                                                    float* __restrict__ csPart) {
  const int tqb = blockIdx.x, bh = blockIdx.y, s = blockIdx.z;
  const int b = bh >> 4, h = bh & 15;
  const int tid = threadIdx.x, lane = tid & 63, w = tid >> 6;
  const int l15 = lane & 15, l4 = lane >> 4;
  const size_t rs = 3072;

  __shared__ ushort Qs[256 * 64];
  __shared__ ushort Ks[3][128 * 64];

  const ushort* Qbase = QKV + (size_t)(b * 2048 + tqb * 256) * rs + h * 64;
  const ushort* Kbase = QKV + (size_t)(b * 2048 + s * 1024) * rs + 1024 + h * 64;
  const float* rz0 = rrz + bh * 2048 + s * 1024;

  const int csl = ((tid & 7) ^ ((tid >> 3) & 7)) * 8;

#pragma unroll
  for (int i = 0; i < 8; i++) {
    int c = i * 256 + tid;
    GLD(Qbase + (size_t)(c >> 3) * rs + csl, (char*)Qs + c * 16);
  }
  const ushort* gk[4];
#pragma unroll
  for (int i = 0; i < 4; i++) {
    int c = i * 256 + tid;
    gk[i] = Kbase + (size_t)(c >> 3) * rs + csl;
    GLD(gk[i], (char*)Ks[0] + c * 16);
    GLD(gk[i] + 128 * rs, (char*)Ks[1] + c * 16);
  }
  asm volatile("s_waitcnt vmcnt(8)" ::: "memory");
  BARRIER();

  bf16x8 qf[4][2];
#pragma unroll
  for (int m = 0; m < 4; m++)
#pragma unroll
    for (int d = 0; d < 2; d++) {
      int r = w * 64 + m * 16 + l15;
      qf[m][d] = *(const bf16x8*)((const char*)Qs + r * 128 + (((d * 4 + l4) ^ (r & 7)) << 4));
    }

  float cs[4][4] = {};
  const f32x4 zero4 = {0.f, 0.f, 0.f, 0.f};

  for (int t = 0; t < 8; ++t) {
    float rz[8];
#pragma unroll
    for (int n = 0; n < 8; n++) rz[n] = rz0[t * 128 + n * 16 + l15];
    if (t < 7)
      asm volatile("s_waitcnt vmcnt(4)" ::: "memory");
    else
      asm volatile("s_waitcnt vmcnt(0)" ::: "memory");
    BARRIER();
    if (t < 6) {
      char* kd = (char*)Ks[(t + 2) % 3];
#pragma unroll
      for (int i = 0; i < 4; i++) {
        int c = i * 256 + tid;
        GLD(gk[i] + (size_t)(t + 2) * 128 * rs, kd + c * 16);
      }
    }
    const char* kb = (const char*)Ks[t % 3];
    f32x4 acc[4][8];
#pragma unroll
    for (int d = 0; d < 2; d++)
#pragma unroll
      for (int n = 0; n < 8; n++) {
        int r = n * 16 + l15;
        bf16x8 kft = *(const bf16x8*)(kb + r * 128 + (((d * 4 + l4) ^ (r & 7)) << 4));
#pragma unroll
        for (int m = 0; m < 4; m++)
          acc[m][n] = __builtin_amdgcn_mfma_f32_16x16x32_bf16(
              qf[m][d], kft, d == 0 ? zero4 : acc[m][n], 0, 0, 0);
      }
#pragma unroll
    for (int m = 0; m < 4; m++)
#pragma unroll
      for (int n = 0; n < 8; n++)
#pragma unroll
        for (int j = 0; j < 4; j++)
          cs[m][j] = fmaf(EXP2(acc[m][n][j]), rz[n], cs[m][j]);
  }

#pragma unroll
  for (int m = 0; m < 4; m++)
#pragma unroll
    for (int j = 0; j < 4; j++) {
      float v = cs[m][j];
      v += __shfl_xor(v, 1, 64);
      v += __shfl_xor(v, 2, 64);
      v += __shfl_xor(v, 4, 64);
      v += __shfl_xor(v, 8, 64);
      if (l15 == 0)
        csPart[(size_t)s * 65536 + bh * 2048 + tqb * 256 + w * 64 + m * 16 + l4 * 4 + j] = v;
    }
}

__global__ void k_mixed(const ushort* __restrict__ QKV, const float* __restrict__ csPart,
                        ushort* __restrict__ mixed) {
  int i = blockIdx.x * 256 + threadIdx.x;
  int row = i >> 7;
  int col = (i & 127) * 8;
  int b = row >> 11, t = row & 2047, h = col >> 6;
  int g = ((b << 4) + h) * 2048 + t;
  float cs = csPart[g] + csPart[65536 + g];
  uint4 raw = *(const uint4*)(QKV + (size_t)row * 3072 + 2048 + col);
  const ushort* pv = (const ushort*)&raw;
  ushort o[8];
#pragma unroll
  for (int k = 0; k < 8; k++) o[k] = f2bf(bf2f(pv[k]) * cs);
  *(uint4*)(mixed + (size_t)row * 1024 + col) = *(uint4*)o;
}

// ---------------- launch ----------------

extern "C" void kernel_launch(void* const* d_in, const int* in_sizes, int n_in,
                              void* d_out, int out_size, void* d_ws, size_t ws_size,
                              hipStream_t stream) {
  const float* x = (const float*)d_in[0];
  const float* Wq = (const float*)d_in[1];
  const float* bq = (const float*)d_in[2];
  const float* Wk = (const float*)d_in[3];
  const float* bk = (const float*)d_in[4];
  const float* Wv = (const float*)d_in[5];
  const float* bv = (const float*)d_in[6];
  const float* Wo = (const float*)d_in[7];
  const float* bo = (const float*)d_in[8];

  char* ws = (char*)d_ws;
  ushort* xb     = (ushort*)(ws);                  // 4096x1024 bf16   (8 MB)
  ushort* Wt     = (ushort*)(ws + 8388608);        // 3072x1024 bf16   (6 MB)
  ushort* Wot    = (ushort*)(ws + 14680064);       // 1024x1024 bf16   (2 MB)
  ushort* QKV    = (ushort*)(ws + 16777216);       // 4096x3072 bf16   (24 MB)
  float* Zpart   = (float*)(ws + 41943040);        // 2x32x2048 f32    (512 KB)
  float* rrz     = (float*)(ws + 42467328);        // 32x2048 f32      (256 KB)
  float* csPart  = (float*)(ws + 42729472);        // 2x32x2048 f32    (512 KB)
  ushort* mixed  = (ushort*)(ws + 43253760);       // 4096x1024 bf16   (8 MB)

  k_cvt_x<<<4096, 256, 0, stream>>>(x, xb, 4096 * 1024 / 4);
  k_prep_w<<<dim3(32, 32, 4), dim3(32, 8), 0, stream>>>(Wq, Wk, Wv, Wo, Wt, Wot);

  k_gemm8<0><<<dim3(12, 16), 512, 0, stream>>>(xb, Wt, QKV, bq, bk, bv, 1024, 3072);
  k_attn_z<<<dim3(8, 32, 2), 256, 0, stream>>>(QKV, Zpart);
  k_rz<<<256, 256, 0, stream>>>(Zpart, rrz);
  k_attn_cs<<<dim3(8, 32, 2), 256, 0, stream>>>(QKV, rrz, csPart);
  k_mixed<<<2048, 256, 0, stream>>>(QKV, csPart, mixed);
  k_gemm<1><<<dim3(8, 32), 256, 0, stream>>>(mixed, Wot, d_out, bo, 4096, 1024, 1024, 1024);
}

// Round 5
// 135.450 us; speedup vs baseline: 1.1199x; 1.1199x over previous
//
#include <hip/hip_runtime.h>
#include <hip/hip_bf16.h>
#include <stdint.h>

typedef __attribute__((ext_vector_type(4))) float f32x4;
typedef __attribute__((ext_vector_type(8))) __bf16 bf16x8;

#define AS1 __attribute__((address_space(1)))
#define AS3 __attribute__((address_space(3)))

#if __has_builtin(__builtin_amdgcn_exp2f)
#define EXP2(x) __builtin_amdgcn_exp2f(x)
#else
#define EXP2(x) exp2f(x)
#endif

__device__ __forceinline__ ushort f2bf(float f) {
  uint32_t u = __builtin_bit_cast(uint32_t, f);
  u += 0x7fffu + ((u >> 16) & 1u);
  return (ushort)(u >> 16);
}
__device__ __forceinline__ float bf2f(ushort h) {
  uint32_t u = ((uint32_t)h) << 16;
  return __builtin_bit_cast(float, u);
}

#define SCK 0.18033688011112042f

#define GLD(src, dst) \
  __builtin_amdgcn_global_load_lds((const AS1 uint32_t*)(src), (AS3 uint32_t*)(dst), 16, 0, 0)

#define BARRIER()                          \
  do {                                     \
    __builtin_amdgcn_sched_barrier(0);     \
    __builtin_amdgcn_s_barrier();          \
    __builtin_amdgcn_sched_barrier(0);     \
  } while (0)

// ---------------- elementwise converts ----------------

__global__ void k_cvt_x(const float* __restrict__ x, ushort* __restrict__ xb, int n4) {
  int i = blockIdx.x * blockDim.x + threadIdx.x;
  if (i >= n4) return;
  float4 v = ((const float4*)x)[i];
  ushort4 o;
  o.x = f2bf(v.x); o.y = f2bf(v.y); o.z = f2bf(v.z); o.w = f2bf(v.w);
  ((ushort4*)xb)[i] = o;
}

__global__ void k_prep_w(const float* __restrict__ Wq, const float* __restrict__ Wk,
                         const float* __restrict__ Wv, const float* __restrict__ Wo,
                         ushort* __restrict__ Wt, ushort* __restrict__ Wot) {
  __shared__ float tile[32][33];
  int z = blockIdx.z;
  const float* src = (z == 0) ? Wq : (z == 1) ? Wk : (z == 2) ? Wv : Wo;
  ushort* dst = (z < 3) ? (Wt + (size_t)z * 1048576) : Wot;
  float scale = (z == 1) ? SCK : 1.0f;
  int k0 = blockIdx.y * 32, n0 = blockIdx.x * 32;
  int tx = threadIdx.x, ty = threadIdx.y;
#pragma unroll
  for (int i = 0; i < 4; i++)
    tile[ty + i * 8][tx] = src[(size_t)(k0 + ty + i * 8) * 1024 + n0 + tx];
  __syncthreads();
#pragma unroll
  for (int i = 0; i < 4; i++)
    dst[(size_t)(n0 + ty + i * 8) * 1024 + k0 + tx] = f2bf(tile[tx][ty + i * 8] * scale);
}

// ---------------- 256x256 pipelined GEMM, 2 sub-phases per K-tile ----------------
template <int MODE>
__global__ __launch_bounds__(512, 2) void k_gemm8(const ushort* __restrict__ A,
                                                  const ushort* __restrict__ Bt,
                                                  void* __restrict__ Cv,
                                                  const float* __restrict__ b0,
                                                  const float* __restrict__ b1,
                                                  const float* __restrict__ b2,
                                                  int K, int ldc) {
  __shared__ char ldsb[131072];
  const int tid = threadIdx.x;
  const int lane = tid & 63;
  const int wid = tid >> 6;
  const int wr = wid >> 2, wc = wid & 3;
  const int l15 = lane & 15, l4 = lane >> 4;
  const int row0 = blockIdx.y * 256;
  const int col0 = blockIdx.x * 256;
  const int T = K >> 5;

  const int swz = ((tid & 3) ^ ((tid >> 3) & 3)) << 3;
  const ushort* Ap = A + (size_t)(row0 + (tid >> 2)) * K + swz;
  const ushort* Bp = Bt + (size_t)(col0 + (tid >> 2)) * K + swz;

#define STAGE_H1(t)                              \
  do {                                           \
    char* bufs = ldsb + (((t) & 3) << 15);       \
    const ushort* pa = Ap + (size_t)(t) * 32;    \
    GLD(pa, bufs + tid * 16);                    \
    GLD(pa + 128 * K, bufs + 8192 + tid * 16);   \
  } while (0)
#define STAGE_H2(t)                              \
  do {                                           \
    char* bufs = ldsb + (((t) & 3) << 15);       \
    const ushort* pb = Bp + (size_t)(t) * 32;    \
    GLD(pb, bufs + 16384 + tid * 16);            \
    GLD(pb + 128 * K, bufs + 24576 + tid * 16);  \
  } while (0)

  int aoffL[8], boffL[4];
#pragma unroll
  for (int m = 0; m < 8; m++) {
    int r = wr * 128 + m * 16 + l15;
    aoffL[m] = r * 64 + ((l4 ^ ((r >> 1) & 3)) << 4);
  }
#pragma unroll
  for (int n = 0; n < 4; n++) {
    int r = wc * 64 + n * 16 + l15;
    boffL[n] = 16384 + r * 64 + ((l4 ^ ((r >> 1) & 3)) << 4);
  }

  f32x4 acc[8][4] = {};

  STAGE_H1(0); STAGE_H2(0);
  STAGE_H1(1); STAGE_H2(1);
  STAGE_H1(2); STAGE_H2(2);
  asm volatile("s_waitcnt vmcnt(8)" ::: "memory");
  BARRIER();

#define PHASE(t, DO_STAGE, VMSTR)                                                     \
  do {                                                                                \
    char* buf = ldsb + (((t) & 3) << 15);                                             \
    {                                                                                 \
      bf16x8 af[4], bfr[4];                                                           \
      _Pragma("unroll") for (int m = 0; m < 4; m++)                                   \
          af[m] = *(const bf16x8*)(buf + aoffL[m]);                                   \
      _Pragma("unroll") for (int n = 0; n < 4; n++)                                   \
          bfr[n] = *(const bf16x8*)(buf + boffL[n]);                                  \
      if (DO_STAGE) STAGE_H1((t) + 3);                                                \
      BARRIER();                                                                      \
      __builtin_amdgcn_s_setprio(1);                                                  \
      _Pragma("unroll") for (int m = 0; m < 4; m++)                                   \
          _Pragma("unroll") for (int n = 0; n < 4; n++)                               \
              acc[m][n] = __builtin_amdgcn_mfma_f32_16x16x32_bf16(af[m], bfr[n],      \
                                                                  acc[m][n], 0, 0, 0);\
      __builtin_amdgcn_s_setprio(0);                                                  \
      BARRIER();                                                                      \
      bf16x8 af2[4];                                                                  \
      _Pragma("unroll") for (int m = 0; m < 4; m++)                                   \
          af2[m] = *(const bf16x8*)(buf + aoffL[m + 4]);                              \
      if (DO_STAGE) STAGE_H2((t) + 3);                                                \
      BARRIER();                                                                      \
      __builtin_amdgcn_s_setprio(1);                                                  \
      _Pragma("unroll") for (int m = 0; m < 4; m++)                                   \
          _Pragma("unroll") for (int n = 0; n < 4; n++)                               \
              acc[m + 4][n] = __builtin_amdgcn_mfma_f32_16x16x32_bf16(                \
                  af2[m], bfr[n], acc[m + 4][n], 0, 0, 0);                            \
      __builtin_amdgcn_s_setprio(0);                                                  \
      asm volatile(VMSTR ::: "memory");                                               \
      BARRIER();                                                                      \
    }                                                                                 \
  } while (0)

  for (int t = 0; t < T - 3; ++t) PHASE(t, true, "s_waitcnt vmcnt(8)");
  PHASE(T - 3, false, "s_waitcnt vmcnt(4)");
  PHASE(T - 2, false, "s_waitcnt vmcnt(0)");
  PHASE(T - 1, false, "s_nop 0");

#undef PHASE
#undef STAGE_H1
#undef STAGE_H2

#pragma unroll
  for (int m = 0; m < 8; m++)
#pragma unroll
    for (int n = 0; n < 4; n++) {
      int colg = col0 + wc * 64 + n * 16 + l15;
      float bias;
      if (MODE == 0) {
        bias = (colg < 1024) ? b0[colg]
                             : ((colg < 2048) ? b1[colg - 1024] * SCK : b2[colg - 2048]);
      } else {
        bias = b0[colg];
      }
#pragma unroll
      for (int j = 0; j < 4; j++) {
        int rowg = row0 + wr * 128 + m * 16 + l4 * 4 + j;
        float v = acc[m][n][j] + bias;
        if (MODE == 0)
          ((ushort*)Cv)[(size_t)rowg * ldc + colg] = f2bf(v);
        else
          ((float*)Cv)[(size_t)rowg * ldc + colg] = v;
      }
    }
}

// ---------------- 128x128 2-phase GEMM for the output projection ----------------
template <int MODE>
__global__ __launch_bounds__(256) void k_gemm(const ushort* __restrict__ A,
                                              const ushort* __restrict__ Bt,
                                              void* __restrict__ Cv,
                                              const float* __restrict__ b0,
                                              int M, int N, int K, int ldc) {
  __shared__ ushort As[128 * 32];
  __shared__ ushort Bs[128 * 32];
  const int tid = threadIdx.x;
  const int lane = tid & 63;
  const int wid = tid >> 6;
  const int wr = wid >> 1, wc = wid & 1;
  const int row0 = blockIdx.y * 128;
  const int col0 = blockIdx.x * 128;
  const int l15 = lane & 15, l4 = lane >> 4;

  f32x4 acc[4][4] = {};

  for (int k0 = 0; k0 < K; k0 += 32) {
    __syncthreads();
#pragma unroll
    for (int i = 0; i < 2; i++) {
      int c = i * 256 + tid;
      int r = c >> 2, cb = c & 3;
      GLD(A + (size_t)(row0 + r) * K + k0 + cb * 8, (char*)As + c * 16);
      GLD(Bt + (size_t)(col0 + r) * K + k0 + cb * 8, (char*)Bs + c * 16);
    }
    __syncthreads();
    bf16x8 av[4], bv[4];
#pragma unroll
    for (int m = 0; m < 4; m++)
      av[m] = *(const bf16x8*)(As + (wr * 64 + m * 16 + l15) * 32 + l4 * 8);
#pragma unroll
    for (int n = 0; n < 4; n++)
      bv[n] = *(const bf16x8*)(Bs + (wc * 64 + n * 16 + l15) * 32 + l4 * 8);
#pragma unroll
    for (int m = 0; m < 4; m++)
#pragma unroll
      for (int n = 0; n < 4; n++)
        acc[m][n] = __builtin_amdgcn_mfma_f32_16x16x32_bf16(av[m], bv[n], acc[m][n], 0, 0, 0);
  }

#pragma unroll
  for (int m = 0; m < 4; m++)
#pragma unroll
    for (int n = 0; n < 4; n++) {
      int colg = col0 + wc * 64 + n * 16 + l15;
      float bias = b0[colg];
#pragma unroll
      for (int j = 0; j < 4; j++) {
        int rowg = row0 + wr * 64 + m * 16 + l4 * 4 + j;
        float v = acc[m][n][j] + bias;
        if (MODE == 0)
          ((ushort*)Cv)[(size_t)rowg * ldc + colg] = f2bf(v);
        else
          ((float*)Cv)[(size_t)rowg * ldc + colg] = v;
      }
    }
}

// ---------------- attention pass 1: Z[tk] = sum_tq exp2(S) ----------------
// Flat grid 512. XCD-colocating decode: the 8 tkb-blocks sharing one (bh,s)
// Q slab get bids congruent mod 8 -> same XCD -> L2-shared Q.
// Block: 256 thr = 4 waves; wave w owns tk rows w*64..+64 of its 256-row K tile.
// Q stream: 128-row tiles, 2-buffer ring, one vmcnt(0)+barrier per tile.
__global__ __launch_bounds__(256, 2) void k_attn_z(const ushort* __restrict__ QKV,
                                                   float* __restrict__ Zpart) {
  const int bid = blockIdx.x;
  const int xcd = bid & 7, kk = bid >> 3;
  const int g = xcd * 8 + (kk >> 3);     // group 0..63 = (s,bh)
  const int tkb = kk & 7;
  const int bh = g & 31, s = g >> 5;
  const int b = bh >> 4, h = bh & 15;
  const int tid = threadIdx.x, lane = tid & 63, w = tid >> 6;
  const int l15 = lane & 15, l4 = lane >> 4;
  const size_t rs = 3072;

  __shared__ ushort Ks[256 * 64];      // 32 KB
  __shared__ ushort Qs[2][128 * 64];   // 32 KB

  const ushort* Kbase = QKV + (size_t)(b * 2048 + tkb * 256) * rs + 1024 + h * 64;
  const ushort* Qbase = QKV + (size_t)(b * 2048 + s * 1024) * rs + h * 64;

  const int csl = ((tid & 7) ^ ((tid >> 3) & 7)) * 8;  // pre-swizzled src offset (ushorts)

#pragma unroll
  for (int i = 0; i < 8; i++) {
    int c = i * 256 + tid;
    GLD(Kbase + (size_t)(c >> 3) * rs + csl, (char*)Ks + c * 16);
  }
  const ushort* gq[4];
#pragma unroll
  for (int i = 0; i < 4; i++) {
    int c = i * 256 + tid;
    gq[i] = Qbase + (size_t)(c >> 3) * rs + csl;
    GLD(gq[i], (char*)Qs[0] + c * 16);
  }
  asm volatile("s_waitcnt vmcnt(0)" ::: "memory");
  BARRIER();

  bf16x8 kf[4][2];
#pragma unroll
  for (int m = 0; m < 4; m++)
#pragma unroll
    for (int d = 0; d < 2; d++) {
      int r = w * 64 + m * 16 + l15;
      kf[m][d] = *(const bf16x8*)((const char*)Ks + r * 128 + (((d * 4 + l4) ^ (r & 7)) << 4));
    }

  float z[4][4] = {};
  const f32x4 zero4 = {0.f, 0.f, 0.f, 0.f};

  for (int t = 0; t < 8; ++t) {
    if (t < 7) {
      char* qd = (char*)Qs[(t + 1) & 1];
#pragma unroll
      for (int i = 0; i < 4; i++) {
        int c = i * 256 + tid;
        GLD(gq[i] + (size_t)(t + 1) * 128 * rs, qd + c * 16);
      }
    }
    const char* qb = (const char*)Qs[t & 1];
    f32x4 acc[4][8];
    __builtin_amdgcn_s_setprio(1);
#pragma unroll
    for (int d = 0; d < 2; d++)
#pragma unroll
      for (int n = 0; n < 8; n++) {
        int r = n * 16 + l15;
        bf16x8 qf = *(const bf16x8*)(qb + r * 128 + (((d * 4 + l4) ^ (r & 7)) << 4));
#pragma unroll
        for (int m = 0; m < 4; m++)
          acc[m][n] = __builtin_amdgcn_mfma_f32_16x16x32_bf16(
              kf[m][d], qf, d == 0 ? zero4 : acc[m][n], 0, 0, 0);
      }
    __builtin_amdgcn_s_setprio(0);
#pragma unroll
    for (int m = 0; m < 4; m++)
#pragma unroll
      for (int n = 0; n < 8; n++)
#pragma unroll
        for (int j = 0; j < 4; j++) z[m][j] += EXP2(acc[m][n][j]);
    if (t < 7) {
      asm volatile("s_waitcnt vmcnt(0)" ::: "memory");
      BARRIER();
    }
  }

#pragma unroll
  for (int m = 0; m < 4; m++)
#pragma unroll
    for (int j = 0; j < 4; j++) {
      float v = z[m][j];
      v += __shfl_xor(v, 1, 64);
      v += __shfl_xor(v, 2, 64);
      v += __shfl_xor(v, 4, 64);
      v += __shfl_xor(v, 8, 64);
      if (l15 == 0)
        Zpart[(size_t)s * 65536 + bh * 2048 + tkb * 256 + w * 64 + m * 16 + l4 * 4 + j] = v;
    }
}

__global__ void k_rz(const float* __restrict__ Zpart, float* __restrict__ rrz) {
  int g = blockIdx.x * 256 + threadIdx.x;
  rrz[g] = 1.0f / (Zpart[g] + Zpart[65536 + g]);
}

// ---------------- attention pass 2: colsum[tq] = sum_tk exp2(S)*rrz[tk] ----
__global__ __launch_bounds__(256, 2) void k_attn_cs(const ushort* __restrict__ QKV,
                                                    const float* __restrict__ rrz,
                                                    float* __restrict__ csPart) {
  const int bid = blockIdx.x;
  const int xcd = bid & 7, kk = bid >> 3;
  const int g = xcd * 8 + (kk >> 3);
  const int tqb = kk & 7;
  const int bh = g & 31, s = g >> 5;
  const int b = bh >> 4, h = bh & 15;
  const int tid = threadIdx.x, lane = tid & 63, w = tid >> 6;
  const int l15 = lane & 15, l4 = lane >> 4;
  const size_t rs = 3072;

  __shared__ ushort Qs[256 * 64];
  __shared__ ushort Ks[2][128 * 64];

  const ushort* Qbase = QKV + (size_t)(b * 2048 + tqb * 256) * rs + h * 64;
  const ushort* Kbase = QKV + (size_t)(b * 2048 + s * 1024) * rs + 1024 + h * 64;
  const float* rz0 = rrz + bh * 2048 + s * 1024;

  const int csl = ((tid & 7) ^ ((tid >> 3) & 7)) * 8;

#pragma unroll
  for (int i = 0; i < 8; i++) {
    int c = i * 256 + tid;
    GLD(Qbase + (size_t)(c >> 3) * rs + csl, (char*)Qs + c * 16);
  }
  const ushort* gk[4];
#pragma unroll
  for (int i = 0; i < 4; i++) {
    int c = i * 256 + tid;
    gk[i] = Kbase + (size_t)(c >> 3) * rs + csl;
    GLD(gk[i], (char*)Ks[0] + c * 16);
  }
  asm volatile("s_waitcnt vmcnt(0)" ::: "memory");
  BARRIER();

  bf16x8 qf[4][2];
#pragma unroll
  for (int m = 0; m < 4; m++)
#pragma unroll
    for (int d = 0; d < 2; d++) {
      int r = w * 64 + m * 16 + l15;
      qf[m][d] = *(const bf16x8*)((const char*)Qs + r * 128 + (((d * 4 + l4) ^ (r & 7)) << 4));
    }

  float cs[4][4] = {};
  const f32x4 zero4 = {0.f, 0.f, 0.f, 0.f};

  for (int t = 0; t < 8; ++t) {
    if (t < 7) {
      char* kd = (char*)Ks[(t + 1) & 1];
#pragma unroll
      for (int i = 0; i < 4; i++) {
        int c = i * 256 + tid;
        GLD(gk[i] + (size_t)(t + 1) * 128 * rs, kd + c * 16);
      }
    }
    float rz[8];
#pragma unroll
    for (int n = 0; n < 8; n++) rz[n] = rz0[t * 128 + n * 16 + l15];
    const char* kb = (const char*)Ks[t & 1];
    f32x4 acc[4][8];
    __builtin_amdgcn_s_setprio(1);
#pragma unroll
    for (int d = 0; d < 2; d++)
#pragma unroll
      for (int n = 0; n < 8; n++) {
        int r = n * 16 + l15;
        bf16x8 kft = *(const bf16x8*)(kb + r * 128 + (((d * 4 + l4) ^ (r & 7)) << 4));
#pragma unroll
        for (int m = 0; m < 4; m++)
          acc[m][n] = __builtin_amdgcn_mfma_f32_16x16x32_bf16(
              qf[m][d], kft, d == 0 ? zero4 : acc[m][n], 0, 0, 0);
      }
    __builtin_amdgcn_s_setprio(0);
#pragma unroll
    for (int m = 0; m < 4; m++)
#pragma unroll
      for (int n = 0; n < 8; n++)
#pragma unroll
        for (int j = 0; j < 4; j++)
          cs[m][j] = fmaf(EXP2(acc[m][n][j]), rz[n], cs[m][j]);
    if (t < 7) {
      asm volatile("s_waitcnt vmcnt(0)" ::: "memory");
      BARRIER();
    }
  }

#pragma unroll
  for (int m = 0; m < 4; m++)
#pragma unroll
    for (int j = 0; j < 4; j++) {
      float v = cs[m][j];
      v += __shfl_xor(v, 1, 64);
      v += __shfl_xor(v, 2, 64);
      v += __shfl_xor(v, 4, 64);
      v += __shfl_xor(v, 8, 64);
      if (l15 == 0)
        csPart[(size_t)s * 65536 + bh * 2048 + tqb * 256 + w * 64 + m * 16 + l4 * 4 + j] = v;
    }
}

__global__ void k_mixed(const ushort* __restrict__ QKV, const float* __restrict__ csPart,
                        ushort* __restrict__ mixed) {
  int i = blockIdx.x * 256 + threadIdx.x;
  int row = i >> 7;
  int col = (i & 127) * 8;
  int b = row >> 11, t = row & 2047, h = col >> 6;
  int g = ((b << 4) + h) * 2048 + t;
  float cs = csPart[g] + csPart[65536 + g];
  uint4 raw = *(const uint4*)(QKV + (size_t)row * 3072 + 2048 + col);
  const ushort* pv = (const ushort*)&raw;
  ushort o[8];
#pragma unroll
  for (int k = 0; k < 8; k++) o[k] = f2bf(bf2f(pv[k]) * cs);
  *(uint4*)(mixed + (size_t)row * 1024 + col) = *(uint4*)o;
}

// ---------------- launch ----------------

extern "C" void kernel_launch(void* const* d_in, const int* in_sizes, int n_in,
                              void* d_out, int out_size, void* d_ws, size_t ws_size,
                              hipStream_t stream) {
  const float* x = (const float*)d_in[0];
  const float* Wq = (const float*)d_in[1];
  const float* bq = (const float*)d_in[2];
  const float* Wk = (const float*)d_in[3];
  const float* bk = (const float*)d_in[4];
  const float* Wv = (const float*)d_in[5];
  const float* bv = (const float*)d_in[6];
  const float* Wo = (const float*)d_in[7];
  const float* bo = (const float*)d_in[8];

  char* ws = (char*)d_ws;
  ushort* xb     = (ushort*)(ws);                  // 4096x1024 bf16   (8 MB)
  ushort* Wt     = (ushort*)(ws + 8388608);        // 3072x1024 bf16   (6 MB)
  ushort* Wot    = (ushort*)(ws + 14680064);       // 1024x1024 bf16   (2 MB)
  ushort* QKV    = (ushort*)(ws + 16777216);       // 4096x3072 bf16   (24 MB)
  float* Zpart   = (float*)(ws + 41943040);        // 2x32x2048 f32    (512 KB)
  float* rrz     = (float*)(ws + 42467328);        // 32x2048 f32      (256 KB)
  float* csPart  = (float*)(ws + 42729472);        // 2x32x2048 f32    (512 KB)
  ushort* mixed  = (ushort*)(ws + 43253760);       // 4096x1024 bf16   (8 MB)

  k_cvt_x<<<4096, 256, 0, stream>>>(x, xb, 4096 * 1024 / 4);
  k_prep_w<<<dim3(32, 32, 4), dim3(32, 8), 0, stream>>>(Wq, Wk, Wv, Wo, Wt, Wot);

  k_gemm8<0><<<dim3(12, 16), 512, 0, stream>>>(xb, Wt, QKV, bq, bk, bv, 1024, 3072);
  k_attn_z<<<512, 256, 0, stream>>>(QKV, Zpart);
  k_rz<<<256, 256, 0, stream>>>(Zpart, rrz);
  k_attn_cs<<<512, 256, 0, stream>>>(QKV, rrz, csPart);
  k_mixed<<<2048, 256, 0, stream>>>(QKV, csPart, mixed);
  k_gemm<1><<<dim3(8, 32), 256, 0, stream>>>(mixed, Wot, d_out, bo, 4096, 1024, 1024, 1024);
}